// Round 3
// baseline (671.980 us; speedup 1.0000x reference)
//
#include <hip/hip_runtime.h>
#include <hip/hip_bf16.h>
#include <stdint.h>

#define NTOK 8192
#define DM   1024
#define DFF  4096
#define NE   8

typedef __bf16 bf16x8 __attribute__((ext_vector_type(8)));
typedef short  short8 __attribute__((ext_vector_type(8)));
typedef float  floatx4 __attribute__((ext_vector_type(4)));

// ---- workspace layout (bytes) ----
#define WS_CNT   0
#define WS_OFF   64
#define WS_TINFO 128                          // [0]=tile count, [1..] packed (e<<16)|mt
#define WS_EIDX  1024
#define WS_PERM  (WS_EIDX + NTOK * 4)
#define WS_XPERM (WS_PERM + NTOK * 4)
#define XPERM_BYTES ((size_t)(NTOK + 128) * DM * 2)
#define WS_WT    (WS_XPERM + XPERM_BYTES)     // reused: upWt then dWt (serial)
#define WT_BYTES ((size_t)NE * DM * DFF * 2)  // 64 MB
#define WS_HPERM_FAST (WS_WT + WT_BYTES)
#define HPERM_BYTES ((size_t)(NTOK + 128) * DFF * 2)
#define FAST_NEED (WS_HPERM_FAST + HPERM_BYTES)   // ~152.4 MB
#define WS_HPERM_FB (WS_XPERM + XPERM_BYTES)      // fallback layout (~85 MB)

__device__ __forceinline__ unsigned short f2bf(float f) {
  union { float f; unsigned u; } v; v.f = f;
  return (unsigned short)((v.u + 0x7FFFu + ((v.u >> 16) & 1u)) >> 16);
}

__device__ __forceinline__ float f4get(const float4& v, int i) {
  return i == 0 ? v.x : i == 1 ? v.y : i == 2 ? v.z : v.w;
}

// async 16B global->LDS (per-lane gaddr, wave-uniform LDS base + lane*16)
__device__ __forceinline__ void gl16(const void* g, void* l) {
  __builtin_amdgcn_global_load_lds(
      (const __attribute__((address_space(1))) unsigned int*)g,
      (__attribute__((address_space(3))) unsigned int*)l, 16, 0, 0);
}

// ---- gate: one wave per token, fp32 logits, argmax(one-hot), eidx ----
__global__ __launch_bounds__(256) void gate_kernel(
    const float* __restrict__ x, const float* __restrict__ gW,
    const float* __restrict__ gb, float* __restrict__ gate_out,
    int* __restrict__ eidx) {
  int wave = threadIdx.x >> 6;
  int lane = threadIdx.x & 63;
  int t = blockIdx.x * 4 + wave;
  const float4* xr = (const float4*)(x + (size_t)t * DM + lane * 16);
  float acc[8] = {0, 0, 0, 0, 0, 0, 0, 0};
#pragma unroll
  for (int q = 0; q < 4; ++q) {
    float4 xv = xr[q];
    int kbase = lane * 16 + q * 4;
#pragma unroll
    for (int d = 0; d < 4; ++d) {
      float xs = f4get(xv, d);
      const float4* g4 = (const float4*)(gW + (size_t)(kbase + d) * NE);
      float4 g0 = g4[0], g1 = g4[1];
      acc[0] += xs * g0.x; acc[1] += xs * g0.y;
      acc[2] += xs * g0.z; acc[3] += xs * g0.w;
      acc[4] += xs * g1.x; acc[5] += xs * g1.y;
      acc[6] += xs * g1.z; acc[7] += xs * g1.w;
    }
  }
#pragma unroll
  for (int off = 32; off > 0; off >>= 1) {
#pragma unroll
    for (int e = 0; e < 8; ++e) acc[e] += __shfl_down(acc[e], off);
  }
  if (lane == 0) {
    float best = acc[0] + gb[0];
    int bi = 0;
#pragma unroll
    for (int e = 1; e < 8; ++e) {
      float v = acc[e] + gb[e];
      if (v > best) { best = v; bi = e; }
    }
#pragma unroll
    for (int e = 0; e < 8; ++e) gate_out[(size_t)t * NE + e] = (e == bi) ? 1.0f : 0.0f;
    eidx[t] = bi;
  }
}

// ---- rank: single block scan -> counts/offs/perm + tile schedule ----
__global__ __launch_bounds__(1024) void rank_kernel(
    const int* __restrict__ eidx, int* __restrict__ counts,
    int* __restrict__ offs, int* __restrict__ tinfo, int* __restrict__ perm) {
  __shared__ unsigned long long sa[1024], sb[1024];
  int tid = threadIdx.x;
  int e8[8];
  unsigned long long ca = 0, cb = 0;
#pragma unroll
  for (int j = 0; j < 8; ++j) {
    int e = eidx[tid * 8 + j];
    e8[j] = e;
    if (e < 4) ca += 1ull << (16 * e);
    else       cb += 1ull << (16 * (e - 4));
  }
  sa[tid] = ca; sb[tid] = cb;
  __syncthreads();
  for (int off = 1; off < 1024; off <<= 1) {
    unsigned long long ta = 0, tb = 0;
    if (tid >= off) { ta = sa[tid - off]; tb = sb[tid - off]; }
    __syncthreads();
    sa[tid] += ta; sb[tid] += tb;
    __syncthreads();
  }
  unsigned long long tot_a = sa[1023], tot_b = sb[1023];
  int cnt_e[8];
#pragma unroll
  for (int e = 0; e < 4; ++e) cnt_e[e] = (int)((tot_a >> (16 * e)) & 0xFFFF);
#pragma unroll
  for (int e = 0; e < 4; ++e) cnt_e[e + 4] = (int)((tot_b >> (16 * e)) & 0xFFFF);
  int off_e[8]; int s = 0;
#pragma unroll
  for (int e = 0; e < 8; ++e) { off_e[e] = s; s += cnt_e[e]; }
  if (tid < 8) { counts[tid] = cnt_e[tid]; offs[tid] = off_e[tid]; }
  if (tid == 0) {
    int nt = 0;
    for (int e = 0; e < 8; ++e) {
      int ntile = (cnt_e[e] + 127) >> 7;
      for (int m = 0; m < ntile; ++m) tinfo[1 + nt++] = (e << 16) | m;
    }
    tinfo[0] = nt;   // <= 71
  }
  unsigned long long ia = sa[tid] - ca, ib = sb[tid] - cb;
  int run[8];
#pragma unroll
  for (int e = 0; e < 4; ++e) run[e] = (int)((ia >> (16 * e)) & 0xFFFF);
#pragma unroll
  for (int e = 0; e < 4; ++e) run[e + 4] = (int)((ib >> (16 * e)) & 0xFFFF);
#pragma unroll
  for (int j = 0; j < 8; ++j) {
    int e = e8[j];
    int pos = off_e[e] + run[e]++;
    perm[pos] = tid * 8 + j;
  }
}

// ---- gather x[perm[p]] -> bf16 xperm[p] ----
__global__ __launch_bounds__(256) void scatter_data_kernel(
    const float* __restrict__ x, const int* __restrict__ perm,
    unsigned short* __restrict__ xperm) {
  int wave = threadIdx.x >> 6, lane = threadIdx.x & 63;
  int p = blockIdx.x * 4 + wave;
  int t = perm[p];
  const float4* xr = (const float4*)(x + (size_t)t * DM);
#pragma unroll
  for (int q = 0; q < 4; ++q) {
    float4 v = xr[q * 64 + lane];
    uint2 pk;
    pk.x = (unsigned)f2bf(v.x) | ((unsigned)f2bf(v.y) << 16);
    pk.y = (unsigned)f2bf(v.z) | ((unsigned)f2bf(v.w) << 16);
    *(uint2*)(xperm + (size_t)p * DM + q * 256 + lane * 4) = pk;
  }
}

// ---- weight convert+transpose: W[e][K][N] fp32 -> Wt[e][N][K] bf16 ----
__global__ __launch_bounds__(256) void wtrans_kernel(
    const float* __restrict__ W, unsigned short* __restrict__ Wt, int K, int N) {
  __shared__ uint2 sT[64 * 17];   // [n 0..63][kg 0..15], stride 17 uint2
  int e = blockIdx.z;
  const float* We = W + (size_t)e * K * N;
  unsigned short* Wte = Wt + (size_t)e * K * N;
  int n0 = blockIdx.x * 64, k0 = blockIdx.y * 64;
  int t = threadIdx.x;
  int kg = t >> 4;        // k = kg*4 .. +3
  int ng = t & 15;        // n = ng*4 .. +3
  float4 r[4];
#pragma unroll
  for (int j = 0; j < 4; ++j)
    r[j] = *(const float4*)(We + (size_t)(k0 + kg * 4 + j) * N + n0 + ng * 4);
#pragma unroll
  for (int i = 0; i < 4; ++i) {
    uint2 pk;
    pk.x = (unsigned)f2bf(f4get(r[0], i)) | ((unsigned)f2bf(f4get(r[1], i)) << 16);
    pk.y = (unsigned)f2bf(f4get(r[2], i)) | ((unsigned)f2bf(f4get(r[3], i)) << 16);
    sT[(ng * 4 + i) * 17 + kg] = pk;
  }
  __syncthreads();
  int n = t >> 2, q = t & 3;      // 4 threads per output row, 16 k each
  uint2 a = sT[n * 17 + q * 4 + 0], b = sT[n * 17 + q * 4 + 1];
  uint2 c = sT[n * 17 + q * 4 + 2], d = sT[n * 17 + q * 4 + 3];
  uint4 w0 = make_uint4(a.x, a.y, b.x, b.y);
  uint4 w1 = make_uint4(c.x, c.y, d.x, d.y);
  uint4* dst = (uint4*)(Wte + (size_t)(n0 + n) * K + k0 + q * 16);
  dst[0] = w0; dst[1] = w1;
}

// ---- out[t][:] = down_b[eidx[t]][:] (bias pre-init for split-K atomics) ----
__global__ __launch_bounds__(256) void init_out_kernel(
    const int* __restrict__ eidx, const float* __restrict__ dB,
    float* __restrict__ out) {
  int wave = threadIdx.x >> 6, lane = threadIdx.x & 63;
  int t = blockIdx.x * 4 + wave;
  int e = eidx[t];
  const float4* src = (const float4*)(dB + (size_t)e * DM);
  float4* dst = (float4*)(out + (size_t)t * DM);
#pragma unroll
  for (int q = 0; q < 4; ++q) dst[q * 64 + lane] = src[q * 64 + lane];
}

// ---- up GEMM (m97-style): h = relu(xperm @ upWt^T + up_b) -> bf16 ----
__global__ __launch_bounds__(256) void up_gemm2(
    const unsigned short* __restrict__ xperm,
    const unsigned short* __restrict__ upWt,   // [E][DFF][DM] bf16
    const float* __restrict__ upB,
    const int* __restrict__ tinfo, const int* __restrict__ offs,
    const int* __restrict__ counts, unsigned short* __restrict__ hperm) {
  if ((int)blockIdx.y >= tinfo[0]) return;
  int pk = tinfo[1 + blockIdx.y];
  int e = pk >> 16, mt = pk & 0xFFFF;
  int cnt = counts[e];
  int row0 = offs[e] + mt * 128;
  int rows_valid = cnt - mt * 128; if (rows_valid > 128) rows_valid = 128;
  int n0 = blockIdx.x * 128;
  const unsigned short* Bg = upWt + (size_t)e * DFF * DM + (size_t)n0 * DM;

  __shared__ __align__(16) unsigned short sA[128 * 32];
  __shared__ __align__(16) unsigned short sB[128 * 32];

  int tid = threadIdx.x, w = tid >> 6, lane = tid & 63;
  int wm = (w >> 1) * 64, wn = (w & 1) * 64;

  int sr = w * 16 + (lane >> 2);       // staging row within 64-row half
  int sseg = (lane & 3) * 8;           // halfword offset (16B seg)
  const unsigned short* ga0 = xperm + (size_t)(row0 + sr) * DM + sseg;
  const unsigned short* ga1 = xperm + (size_t)(row0 + 64 + sr) * DM + sseg;
  const unsigned short* gb0 = Bg + (size_t)sr * DM + sseg;
  const unsigned short* gb1 = Bg + (size_t)(64 + sr) * DM + sseg;
  unsigned short* la0 = sA + w * 512;
  unsigned short* la1 = sA + 2048 + w * 512;
  unsigned short* lb0 = sB + w * 512;
  unsigned short* lb1 = sB + 2048 + w * 512;

  floatx4 acc[4][4];
#pragma unroll
  for (int i = 0; i < 4; ++i)
#pragma unroll
    for (int j = 0; j < 4; ++j) acc[i][j] = (floatx4){0.f, 0.f, 0.f, 0.f};

  for (int k0 = 0; k0 < DM; k0 += 32) {
    __syncthreads();
    gl16(ga0 + k0, la0); gl16(ga1 + k0, la1);
    gl16(gb0 + k0, lb0); gl16(gb1 + k0, lb1);
    __syncthreads();
    bf16x8 a[4], b[4];
#pragma unroll
    for (int i = 0; i < 4; ++i)
      a[i] = *(const bf16x8*)(sA + (wm + i * 16 + (lane & 15)) * 32 + (lane >> 4) * 8);
#pragma unroll
    for (int j = 0; j < 4; ++j)
      b[j] = *(const bf16x8*)(sB + (wn + j * 16 + (lane & 15)) * 32 + (lane >> 4) * 8);
#pragma unroll
    for (int i = 0; i < 4; ++i)
#pragma unroll
      for (int j = 0; j < 4; ++j)
        acc[i][j] = __builtin_amdgcn_mfma_f32_16x16x32_bf16(a[i], b[j], acc[i][j], 0, 0, 0);
  }

  const float* ub = upB + (size_t)e * DFF;
#pragma unroll
  for (int i = 0; i < 4; ++i) {
#pragma unroll
    for (int r = 0; r < 4; ++r) {
      int rl = wm + i * 16 + (lane >> 4) * 4 + r;
      if (rl < rows_valid) {
        size_t rowg = (size_t)(row0 + rl) * DFF;
#pragma unroll
        for (int j = 0; j < 4; ++j) {
          int col = n0 + wn + j * 16 + (lane & 15);
          float v = acc[i][j][r] + ub[col];
          v = v > 0.f ? v : 0.f;
          hperm[rowg + col] = f2bf(v);
        }
      }
    }
  }
}

// ---- down GEMM (m97-style, split-K=2): out += hperm @ dWt^T (atomic) ----
__global__ __launch_bounds__(256) void down_gemm2(
    const unsigned short* __restrict__ hperm,
    const unsigned short* __restrict__ dWt,    // [E][DM][DFF] bf16
    const int* __restrict__ tinfo, const int* __restrict__ offs,
    const int* __restrict__ counts, const int* __restrict__ perm,
    float* __restrict__ out) {
  if ((int)blockIdx.y >= tinfo[0]) return;
  int pk = tinfo[1 + blockIdx.y];
  int e = pk >> 16, mt = pk & 0xFFFF;
  int cnt = counts[e];
  int row0 = offs[e] + mt * 128;
  int rows_valid = cnt - mt * 128; if (rows_valid > 128) rows_valid = 128;
  int n0 = blockIdx.x * 128;
  int kz = blockIdx.z;                         // split-K half
  const unsigned short* Bg = dWt + (size_t)e * DM * DFF + (size_t)n0 * DFF;

  __shared__ __align__(16) unsigned short sA[128 * 32];
  __shared__ __align__(16) unsigned short sB[128 * 32];

  int tid = threadIdx.x, w = tid >> 6, lane = tid & 63;
  int wm = (w >> 1) * 64, wn = (w & 1) * 64;

  int sr = w * 16 + (lane >> 2);
  int sseg = (lane & 3) * 8;
  const unsigned short* ga0 = hperm + (size_t)(row0 + sr) * DFF + sseg;
  const unsigned short* ga1 = hperm + (size_t)(row0 + 64 + sr) * DFF + sseg;
  const unsigned short* gb0 = Bg + (size_t)sr * DFF + sseg;
  const unsigned short* gb1 = Bg + (size_t)(64 + sr) * DFF + sseg;
  unsigned short* la0 = sA + w * 512;
  unsigned short* la1 = sA + 2048 + w * 512;
  unsigned short* lb0 = sB + w * 512;
  unsigned short* lb1 = sB + 2048 + w * 512;

  floatx4 acc[4][4];
#pragma unroll
  for (int i = 0; i < 4; ++i)
#pragma unroll
    for (int j = 0; j < 4; ++j) acc[i][j] = (floatx4){0.f, 0.f, 0.f, 0.f};

  int kbeg = kz * (DFF / 2), kend = kbeg + DFF / 2;
  for (int k0 = kbeg; k0 < kend; k0 += 32) {
    __syncthreads();
    gl16(ga0 + k0, la0); gl16(ga1 + k0, la1);
    gl16(gb0 + k0, lb0); gl16(gb1 + k0, lb1);
    __syncthreads();
    bf16x8 a[4], b[4];
#pragma unroll
    for (int i = 0; i < 4; ++i)
      a[i] = *(const bf16x8*)(sA + (wm + i * 16 + (lane & 15)) * 32 + (lane >> 4) * 8);
#pragma unroll
    for (int j = 0; j < 4; ++j)
      b[j] = *(const bf16x8*)(sB + (wn + j * 16 + (lane & 15)) * 32 + (lane >> 4) * 8);
#pragma unroll
    for (int i = 0; i < 4; ++i)
#pragma unroll
      for (int j = 0; j < 4; ++j)
        acc[i][j] = __builtin_amdgcn_mfma_f32_16x16x32_bf16(a[i], b[j], acc[i][j], 0, 0, 0);
  }

#pragma unroll
  for (int i = 0; i < 4; ++i) {
#pragma unroll
    for (int r = 0; r < 4; ++r) {
      int rl = wm + i * 16 + (lane >> 4) * 4 + r;
      if (rl < rows_valid) {
        int token = perm[row0 + rl];
        size_t og = (size_t)token * DM;
#pragma unroll
        for (int j = 0; j < 4; ++j) {
          int col = n0 + wn + j * 16 + (lane & 15);
          atomicAdd(&out[og + col], acc[i][j][r]);
        }
      }
    }
  }
}

// ======== fallback GEMMs (round-2, fp32 weights staged through VGPRs) ========
__global__ __launch_bounds__(256) void up_gemm_kernel(
    const unsigned short* __restrict__ xperm,
    const float* __restrict__ upW, const float* __restrict__ upB,
    const int* __restrict__ counts, const int* __restrict__ offs,
    unsigned short* __restrict__ hperm) {
  int e = blockIdx.y >> 6;
  int mt = blockIdx.y & 63;
  int cnt = counts[e];
  if (mt * 128 >= cnt) return;
  int row0 = offs[e] + mt * 128;
  int rows_valid = cnt - mt * 128; if (rows_valid > 128) rows_valid = 128;
  int n0 = blockIdx.x * 128;
  const float* Bg = upW + (size_t)e * DM * DFF;
  __shared__ unsigned short sA[128 * 40];
  __shared__ unsigned short sB[128 * 40];
  int tid = threadIdx.x;
  int wave = tid >> 6, lane = tid & 63;
  int wm = (wave >> 1) * 64, wn = (wave & 1) * 64;
  floatx4 acc[4][4];
#pragma unroll
  for (int i = 0; i < 4; ++i)
#pragma unroll
    for (int j = 0; j < 4; ++j) acc[i][j] = (floatx4){0.f, 0.f, 0.f, 0.f};
  int ar = tid >> 2, ac = (tid & 3) * 8, nq = (tid & 31) * 4, kq = (tid >> 5) * 4;
  for (int k0 = 0; k0 < DM; k0 += 32) {
    __syncthreads();
#pragma unroll
    for (int p = 0; p < 2; ++p) {
      int r = p * 64 + ar;
      short8 av = *(const short8*)(xperm + (size_t)(row0 + r) * DM + k0 + ac);
      *(short8*)(sA + r * 40 + ac) = av;
    }
    float4 bv[4];
#pragma unroll
    for (int dk = 0; dk < 4; ++dk)
      bv[dk] = *(const float4*)(Bg + (size_t)(k0 + kq + dk) * DFF + n0 + nq);
#pragma unroll
    for (int dn = 0; dn < 4; ++dn) {
      uint2 pk;
      pk.x = (unsigned)f2bf(f4get(bv[0], dn)) | ((unsigned)f2bf(f4get(bv[1], dn)) << 16);
      pk.y = (unsigned)f2bf(f4get(bv[2], dn)) | ((unsigned)f2bf(f4get(bv[3], dn)) << 16);
      *(uint2*)(sB + (nq + dn) * 40 + kq) = pk;
    }
    __syncthreads();
    bf16x8 a[4], b[4];
#pragma unroll
    for (int i = 0; i < 4; ++i)
      a[i] = *(const bf16x8*)(sA + (wm + i * 16 + (lane & 15)) * 40 + (lane >> 4) * 8);
#pragma unroll
    for (int j = 0; j < 4; ++j)
      b[j] = *(const bf16x8*)(sB + (wn + j * 16 + (lane & 15)) * 40 + (lane >> 4) * 8);
#pragma unroll
    for (int i = 0; i < 4; ++i)
#pragma unroll
      for (int j = 0; j < 4; ++j)
        acc[i][j] = __builtin_amdgcn_mfma_f32_16x16x32_bf16(a[i], b[j], acc[i][j], 0, 0, 0);
  }
  const float* ub = upB + (size_t)e * DFF;
#pragma unroll
  for (int i = 0; i < 4; ++i) {
#pragma unroll
    for (int r = 0; r < 4; ++r) {
      int rl = wm + i * 16 + (lane >> 4) * 4 + r;
      if (rl < rows_valid) {
        size_t rowg = (size_t)(row0 + rl) * DFF;
#pragma unroll
        for (int j = 0; j < 4; ++j) {
          int col = n0 + wn + j * 16 + (lane & 15);
          float v = acc[i][j][r] + ub[col];
          v = v > 0.f ? v : 0.f;
          hperm[rowg + col] = f2bf(v);
        }
      }
    }
  }
}

__global__ __launch_bounds__(256) void down_gemm_kernel(
    const unsigned short* __restrict__ hperm,
    const float* __restrict__ dW, const float* __restrict__ dB,
    const int* __restrict__ counts, const int* __restrict__ offs,
    const int* __restrict__ perm, float* __restrict__ out) {
  int e = blockIdx.y >> 6;
  int mt = blockIdx.y & 63;
  int cnt = counts[e];
  if (mt * 128 >= cnt) return;
  int row0 = offs[e] + mt * 128;
  int rows_valid = cnt - mt * 128; if (rows_valid > 128) rows_valid = 128;
  int n0 = blockIdx.x * 128;
  const float* Bg = dW + (size_t)e * DFF * DM;
  __shared__ unsigned short sA[128 * 40];
  __shared__ unsigned short sB[128 * 40];
  int tid = threadIdx.x;
  int wave = tid >> 6, lane = tid & 63;
  int wm = (wave >> 1) * 64, wn = (wave & 1) * 64;
  floatx4 acc[4][4];
#pragma unroll
  for (int i = 0; i < 4; ++i)
#pragma unroll
    for (int j = 0; j < 4; ++j) acc[i][j] = (floatx4){0.f, 0.f, 0.f, 0.f};
  int ar = tid >> 2, ac = (tid & 3) * 8, nq = (tid & 31) * 4, kq = (tid >> 5) * 4;
  for (int k0 = 0; k0 < DFF; k0 += 32) {
    __syncthreads();
#pragma unroll
    for (int p = 0; p < 2; ++p) {
      int r = p * 64 + ar;
      short8 av = *(const short8*)(hperm + (size_t)(row0 + r) * DFF + k0 + ac);
      *(short8*)(sA + r * 40 + ac) = av;
    }
    float4 bv[4];
#pragma unroll
    for (int dk = 0; dk < 4; ++dk)
      bv[dk] = *(const float4*)(Bg + (size_t)(k0 + kq + dk) * DM + n0 + nq);
#pragma unroll
    for (int dn = 0; dn < 4; ++dn) {
      uint2 pk;
      pk.x = (unsigned)f2bf(f4get(bv[0], dn)) | ((unsigned)f2bf(f4get(bv[1], dn)) << 16);
      pk.y = (unsigned)f2bf(f4get(bv[2], dn)) | ((unsigned)f2bf(f4get(bv[3], dn)) << 16);
      *(uint2*)(sB + (nq + dn) * 40 + kq) = pk;
    }
    __syncthreads();
    bf16x8 a[4], b[4];
#pragma unroll
    for (int i = 0; i < 4; ++i)
      a[i] = *(const bf16x8*)(sA + (wm + i * 16 + (lane & 15)) * 40 + (lane >> 4) * 8);
#pragma unroll
    for (int j = 0; j < 4; ++j)
      b[j] = *(const bf16x8*)(sB + (wn + j * 16 + (lane & 15)) * 40 + (lane >> 4) * 8);
#pragma unroll
    for (int i = 0; i < 4; ++i)
#pragma unroll
      for (int j = 0; j < 4; ++j)
        acc[i][j] = __builtin_amdgcn_mfma_f32_16x16x32_bf16(a[i], b[j], acc[i][j], 0, 0, 0);
  }
  const float* db = dB + (size_t)e * DM;
#pragma unroll
  for (int i = 0; i < 4; ++i) {
#pragma unroll
    for (int r = 0; r < 4; ++r) {
      int rl = wm + i * 16 + (lane >> 4) * 4 + r;
      if (rl < rows_valid) {
        int token = perm[row0 + rl];
        size_t og = (size_t)token * DM;
#pragma unroll
        for (int j = 0; j < 4; ++j) {
          int col = n0 + wn + j * 16 + (lane & 15);
          out[og + col] = acc[i][j][r] + db[col];
        }
      }
    }
  }
}

extern "C" void kernel_launch(void* const* d_in, const int* in_sizes, int n_in,
                              void* d_out, int out_size, void* d_ws, size_t ws_size,
                              hipStream_t stream) {
  const float* x   = (const float*)d_in[0];
  const float* gW  = (const float*)d_in[1];
  const float* gb  = (const float*)d_in[2];
  const float* upW = (const float*)d_in[3];
  const float* upB = (const float*)d_in[4];
  const float* dW  = (const float*)d_in[5];
  const float* dB  = (const float*)d_in[6];
  float* out      = (float*)d_out;
  float* gate_out = out + (size_t)NTOK * DM;

  char* ws = (char*)d_ws;
  int* cnt   = (int*)(ws + WS_CNT);
  int* off   = (int*)(ws + WS_OFF);
  int* tinfo = (int*)(ws + WS_TINFO);
  int* eidx  = (int*)(ws + WS_EIDX);
  int* perm  = (int*)(ws + WS_PERM);
  unsigned short* xperm = (unsigned short*)(ws + WS_XPERM);

  gate_kernel<<<NTOK / 4, 256, 0, stream>>>(x, gW, gb, gate_out, eidx);
  rank_kernel<<<1, 1024, 0, stream>>>(eidx, cnt, off, tinfo, perm);
  scatter_data_kernel<<<NTOK / 4, 256, 0, stream>>>(x, perm, xperm);

  if (ws_size >= FAST_NEED) {
    unsigned short* wt    = (unsigned short*)(ws + WS_WT);
    unsigned short* hperm = (unsigned short*)(ws + WS_HPERM_FAST);
    // upW [E][DM][DFF] -> wt [E][DFF][DM]
    wtrans_kernel<<<dim3(DFF / 64, DM / 64, NE), 256, 0, stream>>>(upW, wt, DM, DFF);
    up_gemm2<<<dim3(DFF / 128, 72), 256, 0, stream>>>(xperm, wt, upB, tinfo, off, cnt, hperm);
    // dW [E][DFF][DM] -> wt [E][DM][DFF]  (reuses buffer, strictly after up_gemm2)
    wtrans_kernel<<<dim3(DM / 64, DFF / 64, NE), 256, 0, stream>>>(dW, wt, DFF, DM);
    init_out_kernel<<<NTOK / 4, 256, 0, stream>>>(eidx, dB, out);
    down_gemm2<<<dim3(DM / 128, 72, 2), 256, 0, stream>>>(hperm, wt, tinfo, off, cnt, perm, out);
  } else {
    unsigned short* hperm = (unsigned short*)(ws + WS_HPERM_FB);
    up_gemm_kernel<<<dim3(DFF / 128, NE * 64), 256, 0, stream>>>(xperm, upW, upB, cnt, off, hperm);
    down_gemm_kernel<<<dim3(DM / 128, NE * 64), 256, 0, stream>>>(hperm, dW, dB, cnt, off, perm, out);
  }
}